// Round 8
// baseline (179.492 us; speedup 1.0000x reference)
//
#include <hip/hip_runtime.h>

// ResidualNetwork forward, MI355X (gfx950).
// Round 28: INLINE-ASM 24-STAGE CHAIN. r21-r27: seven source structures (LDS
// table, ILP2/4, geometry, rotation, PIN4, sched_group_barrier) all compile
// to the SAME ~82us loop (VGPR 40, MfmaUtil 53) -- the scheduler/RA
// canonicalizes to a shared-D serialized form with full MFMA latency exposed
// (~435 cyc/stage vs ~120 hand-scheduled). Demand floor: 3072 MFMA/SIMD x
// 32cyc = 41us. Escape per guide S5: inline-asm the K-loop. One asm block per
// tile-pair: hard regs v48-127 (D0/D1 v48-79, ZERO v80-95, T1 v96-103,
// weight dbuf A/B v104-119, HH v120-127), mm pairs issued back-to-back,
// 19 wait-states (s_nop 7/7/2) before D reads (other waves fill them), LDS
// planes double-buffered with counted lgkmcnt(2), prefetch 2 planes ahead
// (j=10 dummy pf, exit drain lgkmcnt(0) -- leftover ds writes would race
// compiler temps in clobbered regs otherwise). Identical ops in identical
// order -> absmax 0. x-loads issue pre-asm, land under ~3k-cyc body.
// Gates: VGPR 128; MfmaUtil 80-95; main 42-52us; FETCH ~24.7MB; absmax 0.
// If asm lands ~80us at Mfma ~53% -> hw issue-rate ceiling, declare it.

#define NPTS 4194304
#define NBLK 2048
#define WPB 4                       // waves per block (256 threads)
#define NWAVES (NBLK * WPB)         // 8192
#define NTILES (NPTS / 32)          // 131072
#define TPW (NTILES / NWAVES)       // 16 tiles per wave
#define NMM 24
#define ILP 2

typedef _Float16 h8 __attribute__((ext_vector_type(8)));
typedef float v16f __attribute__((ext_vector_type(16)));
typedef unsigned u4v __attribute__((ext_vector_type(4)));

__device__ __forceinline__ unsigned pkrtz(float a, float b) {
    return __builtin_bit_cast(unsigned, __builtin_amdgcn_cvt_pkrtz(a, b));
}

// ---------------- prepack: fused A fragments, sigma-permuted K ---------------
// q=0: layer0 (k rows: x0,x1,x2 @ rr<3, bias col rr==3, pass A[10][rr==3]=1)
// q=1: layer1 dense (w1,b1, pass row 10)
// q=2+2l: fused block A: m0-9=Wr1^T|rr==10:Br1 ; m16-25=Wr2^T|rr==10:Br2+Br3;
//         m26,rr==10: 1 (ones pass)
// q=3+2l: W3 shifted: m16-25 = Wr3^T (rows 0-15 and 26 zero -> srcC passthru)
// q=22: layer8 dense (w8,b8, pass row 10)   q=23: out row m=0 (w9,b9)
__global__ __launch_bounds__(64) void prepack(
    const float* __restrict__ w0, const float* __restrict__ b0,
    const float* __restrict__ w1, const float* __restrict__ b1,
    const float* __restrict__ Wr1, const float* __restrict__ Br1,
    const float* __restrict__ Wr2, const float* __restrict__ Br2,
    const float* __restrict__ Wr3, const float* __restrict__ Br3,
    const float* __restrict__ w8, const float* __restrict__ b8,
    const float* __restrict__ w9, const float* __restrict__ b9,
    h8* __restrict__ tab)
{
    const int q = blockIdx.x, l = threadIdx.x;
    const int m = l & 31, g = l >> 5;
    h8 v;
#pragma unroll
    for (int j = 0; j < 8; ++j) {
        const int rr = (j & 3) + 8 * (j >> 2) + 4 * g;  // sigma(k)
        float a = 0.0f;
        if (q == 0) {
            if (m < 10 && rr < 3)        a = w0[rr * 10 + m];
            else if (m < 10 && rr == 3)  a = b0[m];
            else if (m == 10 && rr == 3) a = 1.0f;
        } else if (q == 1 || q == 22) {
            const float* W = (q == 1) ? w1 : w8;
            const float* B = (q == 1) ? b1 : b8;
            if (m < 10 && rr < 10)        a = W[rr * 10 + m];
            else if (m < 10 && rr == 10)  a = B[m];
            else if (m == 10 && rr == 10) a = 1.0f;
        } else if (q == 23) {
            if (m == 0 && rr < 10)       a = w9[rr];
            else if (m == 0 && rr == 10) a = b9[0];
        } else if (((q - 2) & 1) == 0) {           // fused W1|W2 block
            const int bl = (q - 2) >> 1;
            if (m < 10) {
                if (rr < 10)       a = Wr1[bl * 100 + rr * 10 + m];
                else if (rr == 10) a = Br1[bl * 10 + m];
            } else if (m >= 16 && m < 26) {
                if (rr < 10)       a = Wr2[bl * 100 + rr * 10 + (m - 16)];
                else if (rr == 10) a = Br2[bl * 10 + (m - 16)] + Br3[bl * 10 + (m - 16)];
            } else if (m == 26 && rr == 10) {
                a = 1.0f;                          // ones pass for next layer
            }
        } else {                                   // W3, output rows 16-25
            const int bl = (q - 3) >> 1;
            if (m >= 16 && m < 26 && rr < 10)
                a = Wr3[bl * 100 + rr * 10 + (m - 16)];
        }
        v[j] = (_Float16)a;
    }
    tab[q * 64 + l] = v;
}

// -------------------- asm text building blocks ------------------------------
#define MM(D, A, B, C) "v_mfma_f32_32x32x16_f16 " D ", " A ", " B ", " C "\n"
#define CVT(T, S0, S1) "v_cvt_pkrtz_f16_f32 " T ", " S0 ", " S1 "\n"
#define PKM(T)         "v_pk_max_f16 " T ", " T ", 0\n"
#define NOP19          "s_nop 7\ns_nop 7\ns_nop 2\n"
#define NOP2           "s_nop 1\n"

#define SD0  "v[48:63]"
#define SD1  "v[64:79]"
#define SZ   "v[80:95]"
#define ST10 "v[96:99]"
#define ST11 "v[100:103]"
#define A12A "v[104:107]"
#define A3A  "v[108:111]"
#define A12B "v[112:115]"
#define A3B  "v[116:119]"
#define SH0  "v[120:123]"
#define SH1  "v[124:127]"

// relu+pack of D0/D1 low regs (0-7) or high regs (8-15) into 4 target words
#define RC_LO_D0(T0,T1,T2,T3) \
    CVT(T0,"v48","v49") CVT(T1,"v50","v51") CVT(T2,"v52","v53") CVT(T3,"v54","v55") \
    PKM(T0) PKM(T1) PKM(T2) PKM(T3)
#define RC_LO_D1(T0,T1,T2,T3) \
    CVT(T0,"v64","v65") CVT(T1,"v66","v67") CVT(T2,"v68","v69") CVT(T3,"v70","v71") \
    PKM(T0) PKM(T1) PKM(T2) PKM(T3)
#define RC_HI_D0(T0,T1,T2,T3) \
    CVT(T0,"v56","v57") CVT(T1,"v58","v59") CVT(T2,"v60","v61") CVT(T3,"v62","v63") \
    PKM(T0) PKM(T1) PKM(T2) PKM(T3)
#define RC_HI_D1(T0,T1,T2,T3) \
    CVT(T0,"v72","v73") CVT(T1,"v74","v75") CVT(T2,"v76","v77") CVT(T3,"v78","v79") \
    PKM(T0) PKM(T1) PKM(T2) PKM(T3)

// residual-block pair: planes in (A12,A3); prefetch PF0/PF1 into PD0/PD1
#define PAIR_BLOCK(A12, A3, PF0, PF1, PD0, PD1) \
    "s_waitcnt lgkmcnt(2)\n" \
    MM(SD0, A12, SH0, SZ) \
    MM(SD1, A12, SH1, SZ) \
    NOP19 \
    RC_LO_D0("v96","v97","v98","v99") \
    RC_LO_D1("v100","v101","v102","v103") \
    NOP2 \
    MM(SD0, A3, ST10, SD0) \
    MM(SD1, A3, ST11, SD1) \
    "ds_read_b128 " PD0 ", %[ad] offset:" PF0 "\n" \
    "ds_read_b128 " PD1 ", %[ad] offset:" PF1 "\n" \
    "s_nop 7\ns_nop 7\ns_nop 1\n" \
    RC_HI_D0("v120","v121","v122","v123") \
    RC_HI_D1("v124","v125","v126","v127") \
    NOP2

// L0/L1 pair (set A, planes 0/1024), prefetch planes 4,5 into A
#define PAIR_FIRST \
    "s_waitcnt lgkmcnt(2)\n" \
    MM(SD0, A12A, SH0, SZ) \
    MM(SD1, A12A, SH1, SZ) \
    NOP19 \
    RC_LO_D0("v120","v121","v122","v123") \
    RC_LO_D1("v124","v125","v126","v127") \
    NOP2 \
    MM(SD0, A3A, SH0, SZ) \
    MM(SD1, A3A, SH1, SZ) \
    "ds_read_b128 " A12A ", %[ad] offset:4096\n" \
    "ds_read_b128 " A3A ", %[ad] offset:5120\n" \
    "s_nop 7\ns_nop 7\ns_nop 1\n" \
    RC_LO_D0("v120","v121","v122","v123") \
    RC_LO_D1("v124","v125","v126","v127") \
    NOP2

// L8/L9 pair (set B, planes 22528/23552); outputs D row0 of both chains
#define PAIR_LAST \
    "s_waitcnt lgkmcnt(2)\n" \
    MM(SD0, A12B, SH0, SZ) \
    MM(SD1, A12B, SH1, SZ) \
    NOP19 \
    RC_LO_D0("v120","v121","v122","v123") \
    RC_LO_D1("v124","v125","v126","v127") \
    NOP2 \
    MM(SD0, A3B, SH0, SZ) \
    MM(SD1, A3B, SH1, SZ) \
    NOP19 \
    "s_waitcnt lgkmcnt(0)\n" \
    "v_mov_b32 %[o0], v48\n" \
    "v_mov_b32 %[o1], v64\n"

#define PROLOG \
    "v_mov_b32 v80, 0\n"  "v_mov_b32 v81, 0\n"  "v_mov_b32 v82, 0\n"  "v_mov_b32 v83, 0\n" \
    "v_mov_b32 v84, 0\n"  "v_mov_b32 v85, 0\n"  "v_mov_b32 v86, 0\n"  "v_mov_b32 v87, 0\n" \
    "v_mov_b32 v88, 0\n"  "v_mov_b32 v89, 0\n"  "v_mov_b32 v90, 0\n"  "v_mov_b32 v91, 0\n" \
    "v_mov_b32 v92, 0\n"  "v_mov_b32 v93, 0\n"  "v_mov_b32 v94, 0\n"  "v_mov_b32 v95, 0\n" \
    "v_mov_b32 v120, %[h00]\n" "v_mov_b32 v121, %[h01]\n" \
    "v_mov_b32 v122, 0\n"      "v_mov_b32 v123, 0\n" \
    "v_mov_b32 v124, %[h10]\n" "v_mov_b32 v125, %[h11]\n" \
    "v_mov_b32 v126, 0\n"      "v_mov_b32 v127, 0\n" \
    "ds_read_b128 " A12A ", %[ad] offset:0\n" \
    "ds_read_b128 " A3A  ", %[ad] offset:1024\n" \
    "ds_read_b128 " A12B ", %[ad] offset:2048\n" \
    "ds_read_b128 " A3B  ", %[ad] offset:3072\n"

#define CHAIN_ASM \
    PROLOG \
    PAIR_FIRST \
    PAIR_BLOCK(A12B, A3B,  "6144",  "7168", A12B, A3B) \
    PAIR_BLOCK(A12A, A3A,  "8192",  "9216", A12A, A3A) \
    PAIR_BLOCK(A12B, A3B, "10240", "11264", A12B, A3B) \
    PAIR_BLOCK(A12A, A3A, "12288", "13312", A12A, A3A) \
    PAIR_BLOCK(A12B, A3B, "14336", "15360", A12B, A3B) \
    PAIR_BLOCK(A12A, A3A, "16384", "17408", A12A, A3A) \
    PAIR_BLOCK(A12B, A3B, "18432", "19456", A12B, A3B) \
    PAIR_BLOCK(A12A, A3A, "20480", "21504", A12A, A3A) \
    PAIR_BLOCK(A12B, A3B, "22528", "23552", A12B, A3B) \
    PAIR_BLOCK(A12A, A3A,     "0",     "0", A12A, A3A) \
    PAIR_LAST

#define VCLOB \
    "v48","v49","v50","v51","v52","v53","v54","v55", \
    "v56","v57","v58","v59","v60","v61","v62","v63", \
    "v64","v65","v66","v67","v68","v69","v70","v71", \
    "v72","v73","v74","v75","v76","v77","v78","v79", \
    "v80","v81","v82","v83","v84","v85","v86","v87", \
    "v88","v89","v90","v91","v92","v93","v94","v95", \
    "v96","v97","v98","v99","v100","v101","v102","v103", \
    "v104","v105","v106","v107","v108","v109","v110","v111", \
    "v112","v113","v114","v115","v116","v117","v118","v119", \
    "v120","v121","v122","v123","v124","v125","v126","v127"

// ---- main kernel: asm 24-stage chain, LDS weight table, ILP2 ---------------
__global__ __launch_bounds__(256, 4) void resnet_fwd(
    const float* __restrict__ x,
    const h8* __restrict__ tab,
    float* __restrict__ out)
{
    // stage the 24 A-fragment planes (24*64*16B = 24.6 KB) once per block
    __shared__ h8 sA[NMM * 64];
    for (int i = threadIdx.x; i < NMM * 64; i += 256) sA[i] = tab[i];
    __syncthreads();

    const int lane = threadIdx.x & 63;
    const int wv = blockIdx.x * WPB + (threadIdx.x >> 6);
    const int col = lane & 31;
    const bool lo = lane < 32;

    const unsigned ad = (unsigned)(size_t)(&sA[lane]);   // LDS byte address

    const long p0 = (long)wv * TPW * 32;          // first point index of wave
    const float* px = x + (p0 + col) * 3;         // per-lane x pointer
    float* po = out + p0 + col;                   // per-lane out pointer

    // x for pair 0 (branchless: col valid for all lanes, hi lanes zeroed)
    float xa[ILP][3];
#pragma unroll
    for (int c = 0; c < ILP; ++c) {
        xa[c][0] = px[c * 96 + 0]; xa[c][1] = px[c * 96 + 1];
        xa[c][2] = px[c * 96 + 2];
    }

#pragma unroll 1
    for (int t = 0; t < TPW; t += ILP) {
        // build B words for this pair
        unsigned h00, h01, h10, h11;
        {
            float a0 = lo ? xa[0][0] : 0.f, a1 = lo ? xa[0][1] : 0.f;
            float a2 = lo ? xa[0][2] : 0.f;
            h00 = pkrtz(a0, a1); h01 = pkrtz(a2, lo ? 1.0f : 0.0f);
            float b0_ = lo ? xa[1][0] : 0.f, b1_ = lo ? xa[1][1] : 0.f;
            float b2_ = lo ? xa[1][2] : 0.f;
            h10 = pkrtz(b0_, b1_); h11 = pkrtz(b2_, lo ? 1.0f : 0.0f);
        }

        // issue next pair's x loads; they land under the ~3k-cyc asm body
        const float* pn = px + ILP * 96;
        if (t + ILP < TPW) {
#pragma unroll
            for (int c = 0; c < ILP; ++c) {
                xa[c][0] = pn[c * 96 + 0]; xa[c][1] = pn[c * 96 + 1];
                xa[c][2] = pn[c * 96 + 2];
            }
        }

        float o0, o1;
        asm volatile(
            CHAIN_ASM
            : [o0] "=v"(o0), [o1] "=v"(o1)
            : [h00] "v"(h00), [h01] "v"(h01),
              [h10] "v"(h10), [h11] "v"(h11),
              [ad] "v"(ad)
            : VCLOB);

        if (lo) { po[0] = o0; po[32] = o1; }

        px = pn;
        po += ILP * 32;
    }
}

extern "C" void kernel_launch(void* const* d_in, const int* in_sizes, int n_in,
                              void* d_out, int out_size, void* d_ws, size_t ws_size,
                              hipStream_t stream)
{
    const float* x   = (const float*)d_in[0];
    const float* w0  = (const float*)d_in[1];
    const float* b0  = (const float*)d_in[2];
    const float* w1  = (const float*)d_in[3];
    const float* b1  = (const float*)d_in[4];
    const float* Wr1 = (const float*)d_in[5];
    const float* Br1 = (const float*)d_in[6];
    const float* Wr2 = (const float*)d_in[7];
    const float* Br2 = (const float*)d_in[8];
    const float* Wr3 = (const float*)d_in[9];
    const float* Br3 = (const float*)d_in[10];
    const float* w8  = (const float*)d_in[11];
    const float* b8  = (const float*)d_in[12];
    const float* w9  = (const float*)d_in[13];
    const float* b9  = (const float*)d_in[14];
    float* out = (float*)d_out;
    h8* tab = (h8*)d_ws;   // 24 * 64 * 16B = 24.6 KB scratch

    hipLaunchKernelGGL(prepack, dim3(NMM), dim3(64), 0, stream,
                       w0, b0, w1, b1, Wr1, Br1, Wr2, Br2, Wr3, Br3,
                       w8, b8, w9, b9, tab);

    hipLaunchKernelGGL(resnet_fwd, dim3(NBLK), dim3(256), 0, stream,
                       x, (const h8*)tab, out);
}

// Round 9
// 174.215 us; speedup vs baseline: 1.0303x; 1.0303x over previous
//
#include <hip/hip_runtime.h>

// ResidualNetwork forward, MI355X (gfx950).
// Round 29: RESIDENCY 4->6 BLOCKS/CU. r28's hand-asm landed at 91.6us / 46%
// feed -- compiler scheduling exonerated (9 schedules, same ~50% feed wall).
// Cross-round arithmetic: per-wave stage latency ~400-550cyc (invariant-ish),
// feed = waves x 64/stage => ~50% at the ~3.5 effective waves/SIMD that the
// 24.6KB-LDS + (256,4) geometry allows. Untested lever: MORE independent
// resident waves. Changes vs r21/r25 base (82us, VGPR 40): (1) launch_bounds
// (256,6) -> 6 blocks/CU, 6 waves/SIMD (VGPR cap 84 >> 40); (2) planes
// 0,1,22,23 move from LDS to per-wave regs (16 VGPRs, loaded once from tab)
// -> LDS 20.5KB, 6x20.5=123KB < 160KB fits, and 8 fewer ds_reads/pair.
// Feed model: 1-(1-.28)^6 ~ 80-86%.
// Gates: LDS_Block_Size 20480; VGPR 56-72; Occ 65-75; MfmaUtil 65-80;
// main 55-65us; FETCH ~24.7MB WRITE 16384KB; absmax 0. Decision rule: if Occ
// rises but MfmaUtil stays ~53 -> wave supply exonerated, shared issue/RF
// port becomes prime suspect (MfmaUtil+VALUBusy ~ 105-115% every round).

#define NPTS 4194304
#define NBLK 2048
#define WPB 4                       // waves per block (256 threads)
#define NWAVES (NBLK * WPB)         // 8192
#define NTILES (NPTS / 32)          // 131072
#define TPW (NTILES / NWAVES)       // 16 tiles per wave
#define NMM 24
#define NLDS 20                     // planes 2..21 staged in LDS
#define ILP 2

typedef _Float16 h8 __attribute__((ext_vector_type(8)));
typedef float v16f __attribute__((ext_vector_type(16)));
typedef unsigned u4v __attribute__((ext_vector_type(4)));

__device__ __forceinline__ v16f mm(h8 a, h8 b, v16f c) {
    return __builtin_amdgcn_mfma_f32_32x32x16_f16(a, b, c, 0, 0, 0);
}
__device__ __forceinline__ unsigned pkrtz(float a, float b) {
    return __builtin_bit_cast(unsigned, __builtin_amdgcn_cvt_pkrtz(a, b));
}
// relu on packed f16: 4x v_pk_max_f16
__device__ __forceinline__ h8 relu8(h8 h) {
    h8 z = {0, 0, 0, 0, 0, 0, 0, 0};
    return __builtin_elementwise_max(h, z);
}
// pack+relu of D regs 0-7 (rows sigma(k)): B fragment, sigma order
__device__ __forceinline__ h8 rc_lo(v16f d) {
    u4v u;
    u.x = pkrtz(d[0], d[1]); u.y = pkrtz(d[2], d[3]);
    u.z = pkrtz(d[4], d[5]); u.w = pkrtz(d[6], d[7]);
    return relu8(__builtin_bit_cast(h8, u));
}
// pack+relu of D regs 8-15 (rows 16+sigma(k)): same sigma order
__device__ __forceinline__ h8 rc_hi(v16f d) {
    u4v u;
    u.x = pkrtz(d[8], d[9]);   u.y = pkrtz(d[10], d[11]);
    u.z = pkrtz(d[12], d[13]); u.w = pkrtz(d[14], d[15]);
    return relu8(__builtin_bit_cast(h8, u));
}

// ---------------- prepack: fused A fragments, sigma-permuted K ---------------
// q=0: layer0 (k rows: x0,x1,x2 @ rr<3, bias col rr==3, pass A[10][rr==3]=1)
// q=1: layer1 dense (w1,b1, pass row 10)
// q=2+2l: fused block A: m0-9=Wr1^T|rr==10:Br1 ; m16-25=Wr2^T|rr==10:Br2+Br3;
//         m26,rr==10: 1 (ones pass)
// q=3+2l: W3 shifted: m16-25 = Wr3^T (rows 0-15 and 26 zero -> srcC passthru)
// q=22: layer8 dense (w8,b8, pass row 10)   q=23: out row m=0 (w9,b9)
__global__ __launch_bounds__(64) void prepack(
    const float* __restrict__ w0, const float* __restrict__ b0,
    const float* __restrict__ w1, const float* __restrict__ b1,
    const float* __restrict__ Wr1, const float* __restrict__ Br1,
    const float* __restrict__ Wr2, const float* __restrict__ Br2,
    const float* __restrict__ Wr3, const float* __restrict__ Br3,
    const float* __restrict__ w8, const float* __restrict__ b8,
    const float* __restrict__ w9, const float* __restrict__ b9,
    h8* __restrict__ tab)
{
    const int q = blockIdx.x, l = threadIdx.x;
    const int m = l & 31, g = l >> 5;
    h8 v;
#pragma unroll
    for (int j = 0; j < 8; ++j) {
        const int rr = (j & 3) + 8 * (j >> 2) + 4 * g;  // sigma(k)
        float a = 0.0f;
        if (q == 0) {
            if (m < 10 && rr < 3)        a = w0[rr * 10 + m];
            else if (m < 10 && rr == 3)  a = b0[m];
            else if (m == 10 && rr == 3) a = 1.0f;
        } else if (q == 1 || q == 22) {
            const float* W = (q == 1) ? w1 : w8;
            const float* B = (q == 1) ? b1 : b8;
            if (m < 10 && rr < 10)        a = W[rr * 10 + m];
            else if (m < 10 && rr == 10)  a = B[m];
            else if (m == 10 && rr == 10) a = 1.0f;
        } else if (q == 23) {
            if (m == 0 && rr < 10)       a = w9[rr];
            else if (m == 0 && rr == 10) a = b9[0];
        } else if (((q - 2) & 1) == 0) {           // fused W1|W2 block
            const int bl = (q - 2) >> 1;
            if (m < 10) {
                if (rr < 10)       a = Wr1[bl * 100 + rr * 10 + m];
                else if (rr == 10) a = Br1[bl * 10 + m];
            } else if (m >= 16 && m < 26) {
                if (rr < 10)       a = Wr2[bl * 100 + rr * 10 + (m - 16)];
                else if (rr == 10) a = Br2[bl * 10 + (m - 16)] + Br3[bl * 10 + (m - 16)];
            } else if (m == 26 && rr == 10) {
                a = 1.0f;                          // ones pass for next layer
            }
        } else {                                   // W3, output rows 16-25
            const int bl = (q - 3) >> 1;
            if (m >= 16 && m < 26 && rr < 10)
                a = Wr3[bl * 100 + rr * 10 + (m - 16)];
        }
        v[j] = (_Float16)a;
    }
    tab[q * 64 + l] = v;
}

// ---- main kernel: fused 24-MFMA chain, 20-plane LDS + 4 reg planes ---------
__global__ __launch_bounds__(256, 6) void resnet_fwd(
    const float* __restrict__ x,
    const h8* __restrict__ tab,
    float* __restrict__ out)
{
    const int lane = threadIdx.x & 63;
    const int wv = blockIdx.x * WPB + (threadIdx.x >> 6);
    const int col = lane & 31;
    const bool lo = lane < 32;

    // first/last layer planes live in registers (per-wave, read once)
    const h8 rA0 = tab[0 * 64 + lane];
    const h8 rA1 = tab[1 * 64 + lane];
    const h8 rA8 = tab[22 * 64 + lane];
    const h8 rA9 = tab[23 * 64 + lane];

    // stage residual-block planes 2..21 (20 x 1KB = 20.5 KB) once per block
    __shared__ h8 sA[NLDS * 64];
    for (int i = threadIdx.x; i < NLDS * 64; i += 256) sA[i] = tab[128 + i];
    __syncthreads();

    // resident zero srcC
    v16f zero;
#pragma unroll
    for (int j = 0; j < 16; ++j) zero[j] = 0.0f;
    asm volatile("" : "+v"(zero));

    const long p0 = (long)wv * TPW * 32;          // first point index of wave
    const float* px = x + (p0 + col) * 3;         // per-lane x pointer
    float* po = out + p0 + col;                   // per-lane out pointer

    for (int t = 0; t < TPW; t += ILP) {
        // opaque lane index: stops LICM hoisting the 20 LDS planes into regs
        int ln = lane;
        asm volatile("" : "+v"(ln));
        const h8* wp = &sA[ln];

        // layer-0 B: lanes 0-31 carry (x0,x1,x2,1) in k-rows 0-3; rest zero
        h8 hh[ILP];
#pragma unroll
        for (int c = 0; c < ILP; ++c) {
            float a0 = 0.f, a1 = 0.f, a2 = 0.f;
            if (lo) { a0 = px[c * 96 + 0]; a1 = px[c * 96 + 1];
                      a2 = px[c * 96 + 2]; }
            u4v u;
            u.x = pkrtz(a0, a1); u.y = pkrtz(a2, lo ? 1.0f : 0.0f);
            u.z = 0u; u.w = 0u;
            hh[c] = __builtin_bit_cast(h8, u);
        }

        // layer 0, layer 1 (register planes)
#pragma unroll
        for (int c = 0; c < ILP; ++c) hh[c] = rc_lo(mm(rA0, hh[c], zero));
#pragma unroll
        for (int c = 0; c < ILP; ++c) hh[c] = rc_lo(mm(rA1, hh[c], zero));

        // residual blocks: 2 MFMA each (fused W1|W2, then W3 onto rows 16-26)
#pragma unroll
        for (int bl = 0; bl < 10; ++bl) {
            h8 a12 = wp[(2 * bl) * 64];
            h8 a3  = wp[(2 * bl + 1) * 64];
            v16f d12[ILP];
#pragma unroll
            for (int c = 0; c < ILP; ++c) d12[c] = mm(a12, hh[c], zero);
#pragma unroll
            for (int c = 0; c < ILP; ++c) {
                h8 t1 = rc_lo(d12[c]);
                d12[c] = mm(a3, t1, d12[c]);
            }
#pragma unroll
            for (int c = 0; c < ILP; ++c) hh[c] = rc_hi(d12[c]);
        }

        // layer 8 (register plane)
#pragma unroll
        for (int c = 0; c < ILP; ++c) hh[c] = rc_lo(mm(rA8, hh[c], zero));

        // output layer (register plane): D row 0 = result for 32 points
#pragma unroll
        for (int c = 0; c < ILP; ++c) {
            v16f d = mm(rA9, hh[c], zero);
            if (lo) po[c * 32] = d[0];
        }

        px += ILP * 96;
        po += ILP * 32;
    }
}

extern "C" void kernel_launch(void* const* d_in, const int* in_sizes, int n_in,
                              void* d_out, int out_size, void* d_ws, size_t ws_size,
                              hipStream_t stream)
{
    const float* x   = (const float*)d_in[0];
    const float* w0  = (const float*)d_in[1];
    const float* b0  = (const float*)d_in[2];
    const float* w1  = (const float*)d_in[3];
    const float* b1  = (const float*)d_in[4];
    const float* Wr1 = (const float*)d_in[5];
    const float* Br1 = (const float*)d_in[6];
    const float* Wr2 = (const float*)d_in[7];
    const float* Br2 = (const float*)d_in[8];
    const float* Wr3 = (const float*)d_in[9];
    const float* Br3 = (const float*)d_in[10];
    const float* w8  = (const float*)d_in[11];
    const float* b8  = (const float*)d_in[12];
    const float* w9  = (const float*)d_in[13];
    const float* b9  = (const float*)d_in[14];
    float* out = (float*)d_out;
    h8* tab = (h8*)d_ws;   // 24 * 64 * 16B = 24.6 KB scratch

    hipLaunchKernelGGL(prepack, dim3(NMM), dim3(64), 0, stream,
                       w0, b0, w1, b1, Wr1, Br1, Wr2, Br2, Wr3, Br3,
                       w8, b8, w9, b9, tab);

    hipLaunchKernelGGL(resnet_fwd, dim3(NBLK), dim3(256), 0, stream,
                       x, (const h8*)tab, out);
}